// Round 2
// baseline (4000.073 us; speedup 1.0000x reference)
//
#include <hip/hip_runtime.h>
#include <hip/hip_fp16.h>

#define B_  64
#define T_  1024
#define H_  256
#define G3_ 768
#define D2_ 512

typedef _Float16 h2_t __attribute__((ext_vector_type(2)));

__device__ __forceinline__ h2_t pack2(float x, float y) {
  h2_t r; r[0] = (_Float16)x; r[1] = (_Float16)y; return r;
}

#if __has_builtin(__builtin_amdgcn_fdot2)
__device__ __forceinline__ float fdot2f(h2_t a, h2_t b, float c) {
  return __builtin_amdgcn_fdot2(a, b, c, false);
}
#else
__device__ __forceinline__ float fdot2f(h2_t a, h2_t b, float c) {
  return c + (float)a[0] * (float)b[0] + (float)a[1] * (float)b[1];
}
#endif

// ---------------------------------------------------------------------------
// Persistent GRU recurrence: one block per (batch, direction) stream.
// 768 threads: thread `row` owns W_hh[row, 0:256] as 128 packed-f16 VGPRs.
// h kept in LDS (f32 master + f16 copy for dot2). 1024 sequential steps.
// __launch_bounds__(768,3): 12 waves/CU, VGPR cap 168 (12*168=2016<=2048 OK).
// ---------------------------------------------------------------------------
__global__ __launch_bounds__(768, 3) void gru_rec_k(
    const float* __restrict__ x0,                                        // (B,T) layer-0 input
    const _Float16* __restrict__ xg_f, const _Float16* __restrict__ xg_b,// (B,T,768) f16, layer 1
    const float* __restrict__ whh_f, const float* __restrict__ whh_b,
    const float* __restrict__ bhh_f, const float* __restrict__ bhh_b,
    const float* __restrict__ wih0_f, const float* __restrict__ wih0_b,
    const float* __restrict__ bih0_f, const float* __restrict__ bih0_b,
    _Float16* __restrict__ y,        // (B,T,512): dir d writes cols [d*256, d*256+256)
    float* __restrict__ hT,          // hidden slice base for this layer: [2][B][H]
    const int layer)
{
  const int tid = threadIdx.x;
  const int b   = blockIdx.x >> 1;
  const int dir = blockIdx.x & 1;
  const float* __restrict__ whh = dir ? whh_b : whh_f;
  const float* __restrict__ bhh = dir ? bhh_b : bhh_f;
  const _Float16* __restrict__ xg = dir ? xg_b : xg_f;

  __shared__ h2_t  h2s[H_ / 2];   // h as f16 pairs (dot2 operand)
  __shared__ float hfs[H_];       // h master copy, fp32
  __shared__ float gs[G3_];       // per-step h-gate pre-activations

  // Stage W_hh row into registers as packed f16 (one-time; L2-broadcast across blocks).
  h2_t w[128];
  {
    const float* wr = whh + (size_t)tid * H_;
    #pragma unroll
    for (int i = 0; i < 128; ++i) {
      float2 f = ((const float2*)wr)[i];
      w[i] = pack2(f.x, f.y);
    }
  }
  const float bh = bhh[tid];

  // Layer-0 input projection constants (IN == 1 -> scalar weights per gate row).
  float wr0 = 0.f, wz0 = 0.f, wn0 = 0.f, br0 = 0.f, bz0 = 0.f, bn0 = 0.f;
  if (layer == 0 && tid < H_) {
    const float* wih = dir ? wih0_b : wih0_f;
    const float* bih = dir ? bih0_b : bih0_f;
    wr0 = wih[tid]; wz0 = wih[tid + H_]; wn0 = wih[tid + 2 * H_];
    br0 = bih[tid]; bz0 = bih[tid + H_]; bn0 = bih[tid + 2 * H_];
  }

  if (tid < H_ / 2) h2s[tid] = pack2(0.f, 0.f);
  if (tid < H_)     hfs[tid] = 0.f;
  __syncthreads();

  const size_t brow = (size_t)b * T_;
  for (int t = 0; t < T_; ++t) {
    const int tr = dir ? (T_ - 1 - t) : t;

    // Issue x-gate loads early; latency hides under the dot phase below.
    float xr = 0.f, xz = 0.f, xn = 0.f;
    if (tid < H_) {
      if (layer == 0) {
        const float xv = x0[brow + tr];
        xr = fmaf(xv, wr0, br0);
        xz = fmaf(xv, wz0, bz0);
        xn = fmaf(xv, wn0, bn0);
      } else {
        const _Float16* xp = xg + (brow + tr) * (size_t)G3_;
        xr = (float)xp[tid]; xz = (float)xp[tid + H_]; xn = (float)xp[tid + 2 * H_];
      }
    }

    // hg[row] = W_hh[row,:] . h + b_hh[row]  (f16 inputs, fp32 accumulate; 2 chains for ILP)
    float a0 = bh, a1 = 0.f;
    #pragma unroll
    for (int i = 0; i < 64; ++i) {
      a0 = fdot2f(w[2 * i],     h2s[2 * i],     a0);
      a1 = fdot2f(w[2 * i + 1], h2s[2 * i + 1], a1);
    }
    gs[tid] = a0 + a1;
    __syncthreads();

    if (tid < H_) {
      const float hr = gs[tid], hz = gs[tid + H_], hn = gs[tid + 2 * H_];
      const float r = 1.f / (1.f + __expf(-(xr + hr)));
      const float z = 1.f / (1.f + __expf(-(xz + hz)));
      const float n = tanhf(xn + r * hn);
      const float hnew = (1.f - z) * n + z * hfs[tid];
      hfs[tid] = hnew;
      ((_Float16*)h2s)[tid] = (_Float16)hnew;
      y[(brow + tr) * D2_ + dir * H_ + tid] = (_Float16)hnew;
      if (t == T_ - 1) hT[((size_t)dir * B_ + b) * H_ + tid] = hnew;
    }
    __syncthreads();
  }
}

// ---------------------------------------------------------------------------
// xg = y_l0 @ W_ih_l1^T + b_ih  for both directions (blockIdx.z), f16 output.
// M=65536, N=768, K=512. f16 dot2, fp32 accumulate. 64x64 tile, BK=64.
// ---------------------------------------------------------------------------
__global__ __launch_bounds__(256) void xg_gemm_k(
    const _Float16* __restrict__ A,                                  // (65536, 512)
    const float* __restrict__ Wf, const float* __restrict__ Wb,      // (768, 512)
    const float* __restrict__ bif, const float* __restrict__ bib,    // (768)
    _Float16* __restrict__ Xf, _Float16* __restrict__ Xb)            // (65536, 768) f16
{
  const int dir = blockIdx.z;
  const float* __restrict__ W  = dir ? Wb  : Wf;
  const float* __restrict__ bi = dir ? bib : bif;
  _Float16* __restrict__ X     = dir ? Xb  : Xf;

  const int m0 = blockIdx.x * 64;
  const int n0 = blockIdx.y * 64;
  const int tid = threadIdx.x;
  const int tm = tid >> 4, tn = tid & 15;

  __shared__ h2_t As[64][34];   // [m][k2], stride 34 dwords (8B rows, no conflicts)
  __shared__ h2_t Bs[64][34];   // [n][k2]

  float acc[4][4];
  #pragma unroll
  for (int i = 0; i < 4; ++i)
    #pragma unroll
    for (int j = 0; j < 4; ++j) acc[i][j] = 0.f;

  const int srow = tid >> 2, sq = tid & 3;
  for (int k0 = 0; k0 < 512; k0 += 64) {
    const h2_t* Asrc = (const h2_t*)A + (size_t)(m0 + srow) * 256 + (k0 >> 1) + sq * 8;
    #pragma unroll
    for (int i = 0; i < 8; ++i) As[srow][sq * 8 + i] = Asrc[i];
    const float* Bsrc = W + (size_t)(n0 + srow) * 512 + k0 + sq * 16;
    #pragma unroll
    for (int i = 0; i < 8; ++i) {
      float2 f = ((const float2*)Bsrc)[i];
      Bs[srow][sq * 8 + i] = pack2(f.x, f.y);
    }
    __syncthreads();
    #pragma unroll
    for (int k4 = 0; k4 < 16; ++k4) {
      h2_t av[4][2], bv[4][2];
      #pragma unroll
      for (int i = 0; i < 4; ++i) {
        av[i][0] = As[tm + i * 16][2 * k4];
        av[i][1] = As[tm + i * 16][2 * k4 + 1];
      }
      #pragma unroll
      for (int j = 0; j < 4; ++j) {
        bv[j][0] = Bs[tn + j * 16][2 * k4];
        bv[j][1] = Bs[tn + j * 16][2 * k4 + 1];
      }
      #pragma unroll
      for (int i = 0; i < 4; ++i)
        #pragma unroll
        for (int j = 0; j < 4; ++j) {
          acc[i][j] = fdot2f(av[i][0], bv[j][0], acc[i][j]);
          acc[i][j] = fdot2f(av[i][1], bv[j][1], acc[i][j]);
        }
    }
    __syncthreads();
  }
  #pragma unroll
  for (int j = 0; j < 4; ++j) {
    const int n = n0 + tn + j * 16;
    const float bias = bi[n];
    #pragma unroll
    for (int i = 0; i < 4; ++i) {
      const int m = m0 + tm + i * 16;
      X[(size_t)m * G3_ + n] = (_Float16)(acc[i][j] + bias);
    }
  }
}

// ---------------------------------------------------------------------------
// Classifier: out[m, n] = y_l1[m, :512] . cls_w[n, :] + cls_b[n], n < 8.
// One wave per row; lane-parallel K, shuffle reduce.
// ---------------------------------------------------------------------------
__global__ __launch_bounds__(256) void cls_k(
    const _Float16* __restrict__ Y,   // (65536, 512)
    const float* __restrict__ cw,     // (8, 512)
    const float* __restrict__ cb,     // (8)
    float* __restrict__ out)          // (65536, 8)
{
  const int lane = threadIdx.x & 63;
  const int wv   = threadIdx.x >> 6;
  const int row  = blockIdx.x * 4 + wv;
  const h2_t* Y2 = (const h2_t*)Y + (size_t)row * 256;

  h2_t cwr[8][4];
  #pragma unroll
  for (int n2 = 0; n2 < 8; ++n2)
    #pragma unroll
    for (int i = 0; i < 4; ++i) {
      float2 f = ((const float2*)(cw + n2 * 512))[lane + i * 64];
      cwr[n2][i] = pack2(f.x, f.y);
    }

  float acc[8];
  #pragma unroll
  for (int n2 = 0; n2 < 8; ++n2) acc[n2] = 0.f;
  #pragma unroll
  for (int i = 0; i < 4; ++i) {
    const h2_t yv = Y2[lane + i * 64];
    #pragma unroll
    for (int n2 = 0; n2 < 8; ++n2) acc[n2] = fdot2f(yv, cwr[n2][i], acc[n2]);
  }
  #pragma unroll
  for (int off = 32; off > 0; off >>= 1)
    #pragma unroll
    for (int n2 = 0; n2 < 8; ++n2) acc[n2] += __shfl_down(acc[n2], off, 64);
  if (lane == 0) {
    #pragma unroll
    for (int n2 = 0; n2 < 8; ++n2) out[(size_t)row * 8 + n2] = acc[n2] + cb[n2];
  }
}

extern "C" void kernel_launch(void* const* d_in, const int* in_sizes, int n_in,
                              void* d_out, int out_size, void* d_ws, size_t ws_size,
                              hipStream_t stream)
{
  const float* input = (const float*)d_in[0];
  const float* wih0f = (const float*)d_in[1];
  const float* whh0f = (const float*)d_in[2];
  const float* bih0f = (const float*)d_in[3];
  const float* bhh0f = (const float*)d_in[4];
  const float* wih0b = (const float*)d_in[5];
  const float* whh0b = (const float*)d_in[6];
  const float* bih0b = (const float*)d_in[7];
  const float* bhh0b = (const float*)d_in[8];
  const float* wih1f = (const float*)d_in[9];
  const float* whh1f = (const float*)d_in[10];
  const float* bih1f = (const float*)d_in[11];
  const float* bhh1f = (const float*)d_in[12];
  const float* wih1b = (const float*)d_in[13];
  const float* whh1b = (const float*)d_in[14];
  const float* bih1b = (const float*)d_in[15];
  const float* bhh1b = (const float*)d_in[16];
  const float* clsw  = (const float*)d_in[17];
  const float* clsb  = (const float*)d_in[18];

  float* out = (float*)d_out;
  float* hid = out + (size_t)B_ * T_ * 8;   // hidden: [4][B][H], after (B,T,8) out

  // Workspace layout (256 MiB total):
  //   xg_f  f16 (B,T,768) @ 0        : 100663296 B
  //   xg_b  f16 (B,T,768) @ 96 MiB   : 100663296 B
  //   y0/y1 f16 (B,T,512) @ 192 MiB  :  67108864 B  (y1 overlays y0: y0 dead after GEMM)
  char* ws = (char*)d_ws;
  _Float16* xg_fp = (_Float16*)ws;
  _Float16* xg_bp = (_Float16*)(ws + 100663296u);
  _Float16* y01   = (_Float16*)(ws + 201326592u);

  // Layer 0 recurrence (xg computed inline from scalar input).
  gru_rec_k<<<dim3(2 * B_), dim3(768), 0, stream>>>(
      input, nullptr, nullptr,
      whh0f, whh0b, bhh0f, bhh0b,
      wih0f, wih0b, bih0f, bih0b,
      y01, hid, 0);

  // Layer-1 input projection for both directions (f16 out).
  xg_gemm_k<<<dim3(B_ * T_ / 64, G3_ / 64, 2), dim3(256), 0, stream>>>(
      y01, wih1f, wih1b, bih1f, bih1b, xg_fp, xg_bp);

  // Layer 1 recurrence (writes y1 over the y0 region; reads only xg).
  gru_rec_k<<<dim3(2 * B_), dim3(768), 0, stream>>>(
      nullptr, xg_fp, xg_bp,
      whh1f, whh1b, bhh1f, bhh1b,
      nullptr, nullptr, nullptr, nullptr,
      y01, hid + 2 * B_ * H_, 1);

  // Classifier.
  cls_k<<<dim3(B_ * T_ / 4), dim3(256), 0, stream>>>(y01, clsw, clsb, out);
}

// Round 3
// 3085.718 us; speedup vs baseline: 1.2963x; 1.2963x over previous
//
#include <hip/hip_runtime.h>
#include <hip/hip_fp16.h>

#define B_  64
#define T_  1024
#define H_  256
#define G3_ 768
#define D2_ 512

typedef _Float16 h2_t  __attribute__((ext_vector_type(2)));
typedef _Float16 f16x8 __attribute__((ext_vector_type(8)));
typedef float    f32x4 __attribute__((ext_vector_type(4)));

__device__ __forceinline__ h2_t pack2(float x, float y) {
  h2_t r; r[0] = (_Float16)x; r[1] = (_Float16)y; return r;
}

#if __has_builtin(__builtin_amdgcn_fdot2)
__device__ __forceinline__ float fdot2f(h2_t a, h2_t b, float c) {
  return __builtin_amdgcn_fdot2(a, b, c, false);
}
#else
__device__ __forceinline__ float fdot2f(h2_t a, h2_t b, float c) {
  return c + (float)a[0] * (float)b[0] + (float)a[1] * (float)b[1];
}
#endif

// Inline tanh via native exp2-path exp: no OCML call, nothing forces spills.
__device__ __forceinline__ float tanh_fast(float x) {
  const float ax = fabsf(x);
  const float e  = __expf(-2.0f * ax);          // in (0,1]
  const float t  = (1.0f - e) / (1.0f + e);
  return copysignf(t, x);
}
__device__ __forceinline__ float sigmoid_fast(float x) {
  return 1.0f / (1.0f + __expf(-x));
}

// ---------------------------------------------------------------------------
// Persistent GRU recurrence: one block per (batch, direction) stream.
// 768 threads: thread `row` owns W_hh[row, 0:256] as 128 packed-f16 VGPRs.
// h kept in LDS (f32 master + f16x8 copy read via ds_read_b128).
// __launch_bounds__(768,3): 12 waves/CU, VGPR cap ~170.
// ---------------------------------------------------------------------------
__global__ __launch_bounds__(768, 3) void gru_rec_k(
    const float* __restrict__ x0,                                        // (B,T) layer-0 input
    const _Float16* __restrict__ xg_f, const _Float16* __restrict__ xg_b,// (B,T,768) f16, layer 1
    const float* __restrict__ whh_f, const float* __restrict__ whh_b,
    const float* __restrict__ bhh_f, const float* __restrict__ bhh_b,
    const float* __restrict__ wih0_f, const float* __restrict__ wih0_b,
    const float* __restrict__ bih0_f, const float* __restrict__ bih0_b,
    _Float16* __restrict__ y,        // (B,T,512): dir d writes cols [d*256, d*256+256)
    float* __restrict__ hT,          // hidden slice base for this layer: [2][B][H]
    const int layer)
{
  const int tid = threadIdx.x;
  const int b   = blockIdx.x >> 1;
  const int dir = blockIdx.x & 1;
  const float* __restrict__ whh = dir ? whh_b : whh_f;
  const float* __restrict__ bhh = dir ? bhh_b : bhh_f;
  const _Float16* __restrict__ xg = dir ? xg_b : xg_f;

  __shared__ f16x8 h8s[H_ / 8];   // h as f16, read as b128 (broadcast)
  __shared__ float hfs[H_];       // h master copy, fp32
  __shared__ float gs[G3_];       // per-step h-gate pre-activations

  // Stage W_hh row into registers as packed f16 (one-time).
  h2_t w[128];
  {
    const float* wr = whh + (size_t)tid * H_;
    #pragma unroll
    for (int i = 0; i < 128; ++i) {
      float2 f = ((const float2*)wr)[i];
      w[i] = pack2(f.x, f.y);
    }
  }
  const float bh = bhh[tid];

  // Layer-0 input projection constants (IN == 1 -> scalar weights per gate row).
  float wr0 = 0.f, wz0 = 0.f, wn0 = 0.f, br0 = 0.f, bz0 = 0.f, bn0 = 0.f;
  if (layer == 0 && tid < H_) {
    const float* wih = dir ? wih0_b : wih0_f;
    const float* bih = dir ? bih0_b : bih0_f;
    wr0 = wih[tid]; wz0 = wih[tid + H_]; wn0 = wih[tid + 2 * H_];
    br0 = bih[tid]; bz0 = bih[tid + H_]; bn0 = bih[tid + 2 * H_];
  }

  if (tid < H_ / 8) { f16x8 z = {0,0,0,0,0,0,0,0}; h8s[tid] = z; }
  if (tid < H_)     hfs[tid] = 0.f;
  __syncthreads();

  const size_t brow = (size_t)b * T_;
  for (int t = 0; t < T_; ++t) {
    const int tr = dir ? (T_ - 1 - t) : t;

    // Issue x-gate loads early; latency hides under the dot phase below.
    float xr = 0.f, xz = 0.f, xn = 0.f;
    if (tid < H_) {
      if (layer == 0) {
        const float xv = x0[brow + tr];
        xr = fmaf(xv, wr0, br0);
        xz = fmaf(xv, wz0, bz0);
        xn = fmaf(xv, wn0, bn0);
      } else {
        const _Float16* xp = xg + (brow + tr) * (size_t)G3_;
        xr = (float)xp[tid]; xz = (float)xp[tid + H_]; xn = (float)xp[tid + 2 * H_];
      }
    }

    // hg[row] = W_hh[row,:] . h + b_hh[row]; h read as 32x ds_read_b128.
    float a0 = bh, a1 = 0.f;
    #pragma unroll
    for (int i = 0; i < 32; ++i) {
      const f16x8 hv = h8s[i];
      const h2_t h0 = __builtin_shufflevector(hv, hv, 0, 1);
      const h2_t h1 = __builtin_shufflevector(hv, hv, 2, 3);
      const h2_t h2 = __builtin_shufflevector(hv, hv, 4, 5);
      const h2_t h3 = __builtin_shufflevector(hv, hv, 6, 7);
      a0 = fdot2f(w[4 * i + 0], h0, a0);
      a1 = fdot2f(w[4 * i + 1], h1, a1);
      a0 = fdot2f(w[4 * i + 2], h2, a0);
      a1 = fdot2f(w[4 * i + 3], h3, a1);
    }
    gs[tid] = a0 + a1;
    __syncthreads();

    if (tid < H_) {
      const float hr = gs[tid], hz = gs[tid + H_], hn = gs[tid + 2 * H_];
      const float r = sigmoid_fast(xr + hr);
      const float z = sigmoid_fast(xz + hz);
      const float n = tanh_fast(xn + r * hn);
      const float hnew = (1.f - z) * n + z * hfs[tid];
      hfs[tid] = hnew;
      ((_Float16*)h8s)[tid] = (_Float16)hnew;
      y[(brow + tr) * D2_ + dir * H_ + tid] = (_Float16)hnew;
      if (t == T_ - 1) hT[((size_t)dir * B_ + b) * H_ + tid] = hnew;
    }
    __syncthreads();
  }
}

// ---------------------------------------------------------------------------
// xg = y_l0 @ W_ih_l1^T + b_ih (both dirs via blockIdx.z), f16 output.
// M=65536, N=768, K=512. MFMA f32_16x16x32_f16.
// Tile: BM=128, BN=64, BK=32; 4 waves (2 m x 2 n), per-wave 64x32 output.
// ---------------------------------------------------------------------------
__global__ __launch_bounds__(256) void xg_gemm_k(
    const _Float16* __restrict__ A,                                  // (65536, 512)
    const float* __restrict__ Wf, const float* __restrict__ Wb,      // (768, 512)
    const float* __restrict__ bif, const float* __restrict__ bib,    // (768)
    _Float16* __restrict__ Xf, _Float16* __restrict__ Xb)            // (65536, 768) f16
{
  const int dir = blockIdx.z;
  const float* __restrict__ W  = dir ? Wb  : Wf;
  const float* __restrict__ bi = dir ? bib : bif;
  _Float16* __restrict__ X     = dir ? Xb  : Xf;

  const int m0 = blockIdx.x * 128;
  const int n0 = blockIdx.y * 64;
  const int tid  = threadIdx.x;
  const int lane = tid & 63;
  const int wid  = tid >> 6;
  const int wm   = wid & 1;       // wave row   (0..1) -> 64 rows
  const int wn   = wid >> 1;      // wave col   (0..1) -> 32 cols

  // Row stride 40 f16 = 20 dwords: 16B-aligned rows, <=2-way LDS bank aliasing.
  __shared__ _Float16 As[128][40];
  __shared__ _Float16 Ws[64][40];

  f32x4 acc[4][2];
  #pragma unroll
  for (int i = 0; i < 4; ++i)
    #pragma unroll
    for (int j = 0; j < 2; ++j) acc[i][j] = (f32x4){0.f, 0.f, 0.f, 0.f};

  const int srow = tid >> 2;      // 0..63
  const int skq  = tid & 3;       // k-quarter: 8 f16 each

  const int lrow = lane & 15;
  const int koff = (lane >> 4) * 8;

  for (int k0 = 0; k0 < 512; k0 += 32) {
    // Stage A: 128 rows x 32 f16 (two 64-row halves).
    #pragma unroll
    for (int half = 0; half < 2; ++half) {
      const int r = srow + half * 64;
      const f16x8 v = *(const f16x8*)(A + (size_t)(m0 + r) * 512 + k0 + skq * 8);
      *(f16x8*)&As[r][skq * 8] = v;
    }
    // Stage W: 64 rows x 32 f32 -> f16.
    {
      const float* wsrc = W + (size_t)(n0 + srow) * 512 + k0 + skq * 8;
      const float4 f0 = ((const float4*)wsrc)[0];
      const float4 f1 = ((const float4*)wsrc)[1];
      f16x8 wv;
      wv[0] = (_Float16)f0.x; wv[1] = (_Float16)f0.y; wv[2] = (_Float16)f0.z; wv[3] = (_Float16)f0.w;
      wv[4] = (_Float16)f1.x; wv[5] = (_Float16)f1.y; wv[6] = (_Float16)f1.z; wv[7] = (_Float16)f1.w;
      *(f16x8*)&Ws[srow][skq * 8] = wv;
    }
    __syncthreads();

    f16x8 av[4], bv[2];
    #pragma unroll
    for (int mt = 0; mt < 4; ++mt)
      av[mt] = *(const f16x8*)&As[wm * 64 + mt * 16 + lrow][koff];
    #pragma unroll
    for (int nt = 0; nt < 2; ++nt)
      bv[nt] = *(const f16x8*)&Ws[wn * 32 + nt * 16 + lrow][koff];

    #pragma unroll
    for (int mt = 0; mt < 4; ++mt)
      #pragma unroll
      for (int nt = 0; nt < 2; ++nt)
        acc[mt][nt] = __builtin_amdgcn_mfma_f32_16x16x32_f16(av[mt], bv[nt], acc[mt][nt], 0, 0, 0);
    __syncthreads();
  }

  // Epilogue. C layout: n = lane&15, m = (lane>>4)*4 + reg.
  #pragma unroll
  for (int nt = 0; nt < 2; ++nt) {
    const int gn = n0 + wn * 32 + nt * 16 + lrow;
    const float bias = bi[gn];
    #pragma unroll
    for (int mt = 0; mt < 4; ++mt) {
      #pragma unroll
      for (int j = 0; j < 4; ++j) {
        const int gm = m0 + wm * 64 + mt * 16 + (lane >> 4) * 4 + j;
        X[(size_t)gm * G3_ + gn] = (_Float16)(acc[mt][nt][j] + bias);
      }
    }
  }
}

// ---------------------------------------------------------------------------
// Classifier: out[m, n] = y_l1[m, :512] . cls_w[n, :] + cls_b[n], n < 8.
// ---------------------------------------------------------------------------
__global__ __launch_bounds__(256) void cls_k(
    const _Float16* __restrict__ Y,   // (65536, 512)
    const float* __restrict__ cw,     // (8, 512)
    const float* __restrict__ cb,     // (8)
    float* __restrict__ out)          // (65536, 8)
{
  const int lane = threadIdx.x & 63;
  const int wv   = threadIdx.x >> 6;
  const int row  = blockIdx.x * 4 + wv;
  const h2_t* Y2 = (const h2_t*)Y + (size_t)row * 256;

  h2_t cwr[8][4];
  #pragma unroll
  for (int n2 = 0; n2 < 8; ++n2)
    #pragma unroll
    for (int i = 0; i < 4; ++i) {
      float2 f = ((const float2*)(cw + n2 * 512))[lane + i * 64];
      cwr[n2][i] = pack2(f.x, f.y);
    }

  float acc[8];
  #pragma unroll
  for (int n2 = 0; n2 < 8; ++n2) acc[n2] = 0.f;
  #pragma unroll
  for (int i = 0; i < 4; ++i) {
    const h2_t yv = Y2[lane + i * 64];
    #pragma unroll
    for (int n2 = 0; n2 < 8; ++n2) acc[n2] = fdot2f(yv, cwr[n2][i], acc[n2]);
  }
  #pragma unroll
  for (int off = 32; off > 0; off >>= 1)
    #pragma unroll
    for (int n2 = 0; n2 < 8; ++n2) acc[n2] += __shfl_down(acc[n2], off, 64);
  if (lane == 0) {
    #pragma unroll
    for (int n2 = 0; n2 < 8; ++n2) out[(size_t)row * 8 + n2] = acc[n2] + cb[n2];
  }
}

extern "C" void kernel_launch(void* const* d_in, const int* in_sizes, int n_in,
                              void* d_out, int out_size, void* d_ws, size_t ws_size,
                              hipStream_t stream)
{
  const float* input = (const float*)d_in[0];
  const float* wih0f = (const float*)d_in[1];
  const float* whh0f = (const float*)d_in[2];
  const float* bih0f = (const float*)d_in[3];
  const float* bhh0f = (const float*)d_in[4];
  const float* wih0b = (const float*)d_in[5];
  const float* whh0b = (const float*)d_in[6];
  const float* bih0b = (const float*)d_in[7];
  const float* bhh0b = (const float*)d_in[8];
  const float* wih1f = (const float*)d_in[9];
  const float* whh1f = (const float*)d_in[10];
  const float* bih1f = (const float*)d_in[11];
  const float* bhh1f = (const float*)d_in[12];
  const float* wih1b = (const float*)d_in[13];
  const float* whh1b = (const float*)d_in[14];
  const float* bih1b = (const float*)d_in[15];
  const float* bhh1b = (const float*)d_in[16];
  const float* clsw  = (const float*)d_in[17];
  const float* clsb  = (const float*)d_in[18];

  float* out = (float*)d_out;
  float* hid = out + (size_t)B_ * T_ * 8;   // hidden: [4][B][H], after (B,T,8) out

  // Workspace layout (256 MiB total):
  //   xg_f  f16 (B,T,768) @ 0        : 100663296 B
  //   xg_b  f16 (B,T,768) @ 96 MiB   : 100663296 B
  //   y0/y1 f16 (B,T,512) @ 192 MiB  :  67108864 B  (y1 overlays y0: y0 dead after GEMM)
  char* ws = (char*)d_ws;
  _Float16* xg_fp = (_Float16*)ws;
  _Float16* xg_bp = (_Float16*)(ws + 100663296u);
  _Float16* y01   = (_Float16*)(ws + 201326592u);

  // Layer 0 recurrence (xg computed inline from scalar input).
  gru_rec_k<<<dim3(2 * B_), dim3(768), 0, stream>>>(
      input, nullptr, nullptr,
      whh0f, whh0b, bhh0f, bhh0b,
      wih0f, wih0b, bih0f, bih0b,
      y01, hid, 0);

  // Layer-1 input projection for both directions (f16 out, MFMA).
  xg_gemm_k<<<dim3(B_ * T_ / 128, G3_ / 64, 2), dim3(256), 0, stream>>>(
      y01, wih1f, wih1b, bih1f, bih1b, xg_fp, xg_bp);

  // Layer 1 recurrence (writes y1 over the y0 region; reads only xg).
  gru_rec_k<<<dim3(2 * B_), dim3(768), 0, stream>>>(
      nullptr, xg_fp, xg_bp,
      whh1f, whh1b, bhh1f, bhh1b,
      nullptr, nullptr, nullptr, nullptr,
      y01, hid + 2 * B_ * H_, 1);

  // Classifier.
  cls_k<<<dim3(B_ * T_ / 4), dim3(256), 0, stream>>>(y01, clsw, clsb, out);
}

// Round 4
// 3044.506 us; speedup vs baseline: 1.3139x; 1.0135x over previous
//
#include <hip/hip_runtime.h>
#include <hip/hip_fp16.h>

#define B_  64
#define T_  1024
#define H_  256
#define G3_ 768
#define D2_ 512

typedef _Float16 h2_t  __attribute__((ext_vector_type(2)));
typedef _Float16 f16x8 __attribute__((ext_vector_type(8)));
typedef float    f32x4 __attribute__((ext_vector_type(4)));

__device__ __forceinline__ h2_t pack2(float x, float y) {
  h2_t r; r[0] = (_Float16)x; r[1] = (_Float16)y; return r;
}

#if __has_builtin(__builtin_amdgcn_fdot2)
__device__ __forceinline__ float fdot2f(h2_t a, h2_t b, float c) {
  return __builtin_amdgcn_fdot2(a, b, c, false);
}
#else
__device__ __forceinline__ float fdot2f(h2_t a, h2_t b, float c) {
  return c + (float)a[0] * (float)b[0] + (float)a[1] * (float)b[1];
}
#endif

__device__ __forceinline__ float tanh_fast(float x) {
  const float ax = fabsf(x);
  const float e  = __expf(-2.0f * ax);
  const float t  = (1.0f - e) / (1.0f + e);
  return copysignf(t, x);
}
__device__ __forceinline__ float sigmoid_fast(float x) {
  return 1.0f / (1.0f + __expf(-x));
}

// ---------------------------------------------------------------------------
// Persistent GRU recurrence: one block per (batch, direction) stream.
// Thread `row` owns W_hh[row, 0:256] as 128 NAMED h2_t registers (no array:
// arrays demote to scratch — round-3 evidence: VGPR=84 with w[128]).
// h kept in LDS as f16 (ds_read_b128 broadcast); h_prev in a register.
// __launch_bounds__(768,3): block = 12 waves = 3/SIMD, VGPR cap 170.
// ---------------------------------------------------------------------------
__global__ __launch_bounds__(768, 3) void gru_rec_k(
    const float* __restrict__ x0,                                        // (B,T) layer-0 input
    const _Float16* __restrict__ xg_f, const _Float16* __restrict__ xg_b,// (B,T,768) f16, layer 1
    const float* __restrict__ whh_f, const float* __restrict__ whh_b,
    const float* __restrict__ bhh_f, const float* __restrict__ bhh_b,
    const float* __restrict__ wih0_f, const float* __restrict__ wih0_b,
    const float* __restrict__ bih0_f, const float* __restrict__ bih0_b,
    _Float16* __restrict__ y,        // (B,T,512): dir d writes cols [d*256, d*256+256)
    float* __restrict__ hT,          // hidden slice base for this layer: [2][B][H]
    const int layer)
{
  const int tid = threadIdx.x;
  const int b   = blockIdx.x >> 1;
  const int dir = blockIdx.x & 1;
  const float* __restrict__ whh = dir ? whh_b : whh_f;
  const float* __restrict__ bhh = dir ? bhh_b : bhh_f;
  const _Float16* __restrict__ xg = dir ? xg_b : xg_f;

  __shared__ f16x8 h8s[H_ / 8];   // h as f16, read as b128 (broadcast)
  __shared__ float gs[G3_];       // per-step h-gate pre-activations

  // 128 named weight registers.
  h2_t w_0,w_1,w_2,w_3,w_4,w_5,w_6,w_7,w_8,w_9,w_10,w_11,w_12,w_13,w_14,w_15,
       w_16,w_17,w_18,w_19,w_20,w_21,w_22,w_23,w_24,w_25,w_26,w_27,w_28,w_29,w_30,w_31,
       w_32,w_33,w_34,w_35,w_36,w_37,w_38,w_39,w_40,w_41,w_42,w_43,w_44,w_45,w_46,w_47,
       w_48,w_49,w_50,w_51,w_52,w_53,w_54,w_55,w_56,w_57,w_58,w_59,w_60,w_61,w_62,w_63,
       w_64,w_65,w_66,w_67,w_68,w_69,w_70,w_71,w_72,w_73,w_74,w_75,w_76,w_77,w_78,w_79,
       w_80,w_81,w_82,w_83,w_84,w_85,w_86,w_87,w_88,w_89,w_90,w_91,w_92,w_93,w_94,w_95,
       w_96,w_97,w_98,w_99,w_100,w_101,w_102,w_103,w_104,w_105,w_106,w_107,w_108,w_109,w_110,w_111,
       w_112,w_113,w_114,w_115,w_116,w_117,w_118,w_119,w_120,w_121,w_122,w_123,w_124,w_125,w_126,w_127;

  {
    const float2* wr2 = (const float2*)(whh + (size_t)tid * H_);
#define LW(i) { const float2 f_ = wr2[i]; w_##i = pack2(f_.x, f_.y); }
    LW(0) LW(1) LW(2) LW(3) LW(4) LW(5) LW(6) LW(7)
    LW(8) LW(9) LW(10) LW(11) LW(12) LW(13) LW(14) LW(15)
    LW(16) LW(17) LW(18) LW(19) LW(20) LW(21) LW(22) LW(23)
    LW(24) LW(25) LW(26) LW(27) LW(28) LW(29) LW(30) LW(31)
    LW(32) LW(33) LW(34) LW(35) LW(36) LW(37) LW(38) LW(39)
    LW(40) LW(41) LW(42) LW(43) LW(44) LW(45) LW(46) LW(47)
    LW(48) LW(49) LW(50) LW(51) LW(52) LW(53) LW(54) LW(55)
    LW(56) LW(57) LW(58) LW(59) LW(60) LW(61) LW(62) LW(63)
    LW(64) LW(65) LW(66) LW(67) LW(68) LW(69) LW(70) LW(71)
    LW(72) LW(73) LW(74) LW(75) LW(76) LW(77) LW(78) LW(79)
    LW(80) LW(81) LW(82) LW(83) LW(84) LW(85) LW(86) LW(87)
    LW(88) LW(89) LW(90) LW(91) LW(92) LW(93) LW(94) LW(95)
    LW(96) LW(97) LW(98) LW(99) LW(100) LW(101) LW(102) LW(103)
    LW(104) LW(105) LW(106) LW(107) LW(108) LW(109) LW(110) LW(111)
    LW(112) LW(113) LW(114) LW(115) LW(116) LW(117) LW(118) LW(119)
    LW(120) LW(121) LW(122) LW(123) LW(124) LW(125) LW(126) LW(127)
#undef LW
  }
  const float bh = bhh[tid];

  // Layer-0 input projection constants (IN == 1 -> scalar weights per gate row).
  float wr0 = 0.f, wz0 = 0.f, wn0 = 0.f, br0 = 0.f, bz0 = 0.f, bn0 = 0.f;
  if (layer == 0 && tid < H_) {
    const float* wih = dir ? wih0_b : wih0_f;
    const float* bih = dir ? bih0_b : bih0_f;
    wr0 = wih[tid]; wz0 = wih[tid + H_]; wn0 = wih[tid + 2 * H_];
    br0 = bih[tid]; bz0 = bih[tid + H_]; bn0 = bih[tid + 2 * H_];
  }

  if (tid < H_ / 8) { f16x8 z = {0,0,0,0,0,0,0,0}; h8s[tid] = z; }
  float hprev = 0.f;   // thread tid<256 owns hidden unit `tid`
  __syncthreads();

  const size_t brow = (size_t)b * T_;
  for (int t = 0; t < T_; ++t) {
    const int tr = dir ? (T_ - 1 - t) : t;

    // Issue x-gate loads early; latency hides under the dot phase below.
    float xr = 0.f, xz = 0.f, xn = 0.f;
    if (tid < H_) {
      if (layer == 0) {
        const float xv = x0[brow + tr];
        xr = fmaf(xv, wr0, br0);
        xz = fmaf(xv, wz0, bz0);
        xn = fmaf(xv, wn0, bn0);
      } else {
        const _Float16* xp = xg + (brow + tr) * (size_t)G3_;
        xr = (float)xp[tid]; xz = (float)xp[tid + H_]; xn = (float)xp[tid + 2 * H_];
      }
    }

    // hg[row] = W_hh[row,:] . h + b_hh[row]; h via 32x ds_read_b128 (uniform).
    float a0 = bh, a1 = 0.f;
#define DG(g,i0,i1,i2,i3) { const f16x8 hv_ = h8s[g]; \
    a0 = fdot2f(w_##i0, __builtin_shufflevector(hv_, hv_, 0, 1), a0); \
    a1 = fdot2f(w_##i1, __builtin_shufflevector(hv_, hv_, 2, 3), a1); \
    a0 = fdot2f(w_##i2, __builtin_shufflevector(hv_, hv_, 4, 5), a0); \
    a1 = fdot2f(w_##i3, __builtin_shufflevector(hv_, hv_, 6, 7), a1); }
    DG(0,0,1,2,3)      DG(1,4,5,6,7)      DG(2,8,9,10,11)     DG(3,12,13,14,15)
    DG(4,16,17,18,19)  DG(5,20,21,22,23)  DG(6,24,25,26,27)   DG(7,28,29,30,31)
    DG(8,32,33,34,35)  DG(9,36,37,38,39)  DG(10,40,41,42,43)  DG(11,44,45,46,47)
    DG(12,48,49,50,51) DG(13,52,53,54,55) DG(14,56,57,58,59)  DG(15,60,61,62,63)
    DG(16,64,65,66,67) DG(17,68,69,70,71) DG(18,72,73,74,75)  DG(19,76,77,78,79)
    DG(20,80,81,82,83) DG(21,84,85,86,87) DG(22,88,89,90,91)  DG(23,92,93,94,95)
    DG(24,96,97,98,99) DG(25,100,101,102,103) DG(26,104,105,106,107) DG(27,108,109,110,111)
    DG(28,112,113,114,115) DG(29,116,117,118,119) DG(30,120,121,122,123) DG(31,124,125,126,127)
#undef DG
    gs[tid] = a0 + a1;
    __syncthreads();

    if (tid < H_) {
      const float hr = gs[tid], hz = gs[tid + H_], hn = gs[tid + 2 * H_];
      const float r = sigmoid_fast(xr + hr);
      const float z = sigmoid_fast(xz + hz);
      const float n = tanh_fast(xn + r * hn);
      const float hnew = (1.f - z) * n + z * hprev;
      hprev = hnew;
      ((_Float16*)h8s)[tid] = (_Float16)hnew;
      y[(brow + tr) * D2_ + dir * H_ + tid] = (_Float16)hnew;
      if (t == T_ - 1) hT[((size_t)dir * B_ + b) * H_ + tid] = hnew;
    }
    __syncthreads();
  }
}

// ---------------------------------------------------------------------------
// xg = y_l0 @ W_ih_l1^T + b_ih (both dirs via blockIdx.z), f16 output.
// M=65536, N=768, K=512. MFMA f32_16x16x32_f16.
// Tile: BM=128, BN=64, BK=32; 4 waves (2 m x 2 n), per-wave 64x32 output.
// ---------------------------------------------------------------------------
__global__ __launch_bounds__(256) void xg_gemm_k(
    const _Float16* __restrict__ A,                                  // (65536, 512)
    const float* __restrict__ Wf, const float* __restrict__ Wb,      // (768, 512)
    const float* __restrict__ bif, const float* __restrict__ bib,    // (768)
    _Float16* __restrict__ Xf, _Float16* __restrict__ Xb)            // (65536, 768) f16
{
  const int dir = blockIdx.z;
  const float* __restrict__ W  = dir ? Wb  : Wf;
  const float* __restrict__ bi = dir ? bib : bif;
  _Float16* __restrict__ X     = dir ? Xb  : Xf;

  const int m0 = blockIdx.x * 128;
  const int n0 = blockIdx.y * 64;
  const int tid  = threadIdx.x;
  const int lane = tid & 63;
  const int wid  = tid >> 6;
  const int wm   = wid & 1;
  const int wn   = wid >> 1;

  __shared__ _Float16 As[128][40];
  __shared__ _Float16 Ws[64][40];

  f32x4 acc[4][2];
  #pragma unroll
  for (int i = 0; i < 4; ++i)
    #pragma unroll
    for (int j = 0; j < 2; ++j) acc[i][j] = (f32x4){0.f, 0.f, 0.f, 0.f};

  const int srow = tid >> 2;
  const int skq  = tid & 3;

  const int lrow = lane & 15;
  const int koff = (lane >> 4) * 8;

  for (int k0 = 0; k0 < 512; k0 += 32) {
    #pragma unroll
    for (int half = 0; half < 2; ++half) {
      const int r = srow + half * 64;
      const f16x8 v = *(const f16x8*)(A + (size_t)(m0 + r) * 512 + k0 + skq * 8);
      *(f16x8*)&As[r][skq * 8] = v;
    }
    {
      const float* wsrc = W + (size_t)(n0 + srow) * 512 + k0 + skq * 8;
      const float4 f0 = ((const float4*)wsrc)[0];
      const float4 f1 = ((const float4*)wsrc)[1];
      f16x8 wv;
      wv[0] = (_Float16)f0.x; wv[1] = (_Float16)f0.y; wv[2] = (_Float16)f0.z; wv[3] = (_Float16)f0.w;
      wv[4] = (_Float16)f1.x; wv[5] = (_Float16)f1.y; wv[6] = (_Float16)f1.z; wv[7] = (_Float16)f1.w;
      *(f16x8*)&Ws[srow][skq * 8] = wv;
    }
    __syncthreads();

    f16x8 av[4], bv[2];
    #pragma unroll
    for (int mt = 0; mt < 4; ++mt)
      av[mt] = *(const f16x8*)&As[wm * 64 + mt * 16 + lrow][koff];
    #pragma unroll
    for (int nt = 0; nt < 2; ++nt)
      bv[nt] = *(const f16x8*)&Ws[wn * 32 + nt * 16 + lrow][koff];

    #pragma unroll
    for (int mt = 0; mt < 4; ++mt)
      #pragma unroll
      for (int nt = 0; nt < 2; ++nt)
        acc[mt][nt] = __builtin_amdgcn_mfma_f32_16x16x32_f16(av[mt], bv[nt], acc[mt][nt], 0, 0, 0);
    __syncthreads();
  }

  #pragma unroll
  for (int nt = 0; nt < 2; ++nt) {
    const int gn = n0 + wn * 32 + nt * 16 + lrow;
    const float bias = bi[gn];
    #pragma unroll
    for (int mt = 0; mt < 4; ++mt) {
      #pragma unroll
      for (int j = 0; j < 4; ++j) {
        const int gm = m0 + wm * 64 + mt * 16 + (lane >> 4) * 4 + j;
        X[(size_t)gm * G3_ + gn] = (_Float16)(acc[mt][nt][j] + bias);
      }
    }
  }
}

// ---------------------------------------------------------------------------
// Classifier: out[m, n] = y_l1[m, :512] . cls_w[n, :] + cls_b[n], n < 8.
// ---------------------------------------------------------------------------
__global__ __launch_bounds__(256) void cls_k(
    const _Float16* __restrict__ Y,   // (65536, 512)
    const float* __restrict__ cw,     // (8, 512)
    const float* __restrict__ cb,     // (8)
    float* __restrict__ out)          // (65536, 8)
{
  const int lane = threadIdx.x & 63;
  const int wv   = threadIdx.x >> 6;
  const int row  = blockIdx.x * 4 + wv;
  const h2_t* Y2 = (const h2_t*)Y + (size_t)row * 256;

  h2_t cwr[8][4];
  #pragma unroll
  for (int n2 = 0; n2 < 8; ++n2)
    #pragma unroll
    for (int i = 0; i < 4; ++i) {
      float2 f = ((const float2*)(cw + n2 * 512))[lane + i * 64];
      cwr[n2][i] = pack2(f.x, f.y);
    }

  float acc[8];
  #pragma unroll
  for (int n2 = 0; n2 < 8; ++n2) acc[n2] = 0.f;
  #pragma unroll
  for (int i = 0; i < 4; ++i) {
    const h2_t yv = Y2[lane + i * 64];
    #pragma unroll
    for (int n2 = 0; n2 < 8; ++n2) acc[n2] = fdot2f(yv, cwr[n2][i], acc[n2]);
  }
  #pragma unroll
  for (int off = 32; off > 0; off >>= 1)
    #pragma unroll
    for (int n2 = 0; n2 < 8; ++n2) acc[n2] += __shfl_down(acc[n2], off, 64);
  if (lane == 0) {
    #pragma unroll
    for (int n2 = 0; n2 < 8; ++n2) out[(size_t)row * 8 + n2] = acc[n2] + cb[n2];
  }
}

extern "C" void kernel_launch(void* const* d_in, const int* in_sizes, int n_in,
                              void* d_out, int out_size, void* d_ws, size_t ws_size,
                              hipStream_t stream)
{
  const float* input = (const float*)d_in[0];
  const float* wih0f = (const float*)d_in[1];
  const float* whh0f = (const float*)d_in[2];
  const float* bih0f = (const float*)d_in[3];
  const float* bhh0f = (const float*)d_in[4];
  const float* wih0b = (const float*)d_in[5];
  const float* whh0b = (const float*)d_in[6];
  const float* bih0b = (const float*)d_in[7];
  const float* bhh0b = (const float*)d_in[8];
  const float* wih1f = (const float*)d_in[9];
  const float* whh1f = (const float*)d_in[10];
  const float* bih1f = (const float*)d_in[11];
  const float* bhh1f = (const float*)d_in[12];
  const float* wih1b = (const float*)d_in[13];
  const float* whh1b = (const float*)d_in[14];
  const float* bih1b = (const float*)d_in[15];
  const float* bhh1b = (const float*)d_in[16];
  const float* clsw  = (const float*)d_in[17];
  const float* clsb  = (const float*)d_in[18];

  float* out = (float*)d_out;
  float* hid = out + (size_t)B_ * T_ * 8;   // hidden: [4][B][H], after (B,T,8) out

  // Workspace layout (256 MiB):
  //   xg_f  f16 (B,T,768) @ 0        : 100663296 B
  //   xg_b  f16 (B,T,768) @ 96 MiB   : 100663296 B
  //   y0/y1 f16 (B,T,512) @ 192 MiB  :  67108864 B  (y1 overlays y0)
  char* ws = (char*)d_ws;
  _Float16* xg_fp = (_Float16*)ws;
  _Float16* xg_bp = (_Float16*)(ws + 100663296u);
  _Float16* y01   = (_Float16*)(ws + 201326592u);

  gru_rec_k<<<dim3(2 * B_), dim3(768), 0, stream>>>(
      input, nullptr, nullptr,
      whh0f, whh0b, bhh0f, bhh0b,
      wih0f, wih0b, bih0f, bih0b,
      y01, hid, 0);

  xg_gemm_k<<<dim3(B_ * T_ / 128, G3_ / 64, 2), dim3(256), 0, stream>>>(
      y01, wih1f, wih1b, bih1f, bih1b, xg_fp, xg_bp);

  gru_rec_k<<<dim3(2 * B_), dim3(768), 0, stream>>>(
      nullptr, xg_fp, xg_bp,
      whh1f, whh1b, bhh1f, bhh1b,
      nullptr, nullptr, nullptr, nullptr,
      y01, hid + 2 * B_ * H_, 1);

  cls_k<<<dim3(B_ * T_ / 4), dim3(256), 0, stream>>>(y01, clsw, clsb, out);
}